// Round 1
// baseline (2197.832 us; speedup 1.0000x reference)
//
#include <hip/hip_runtime.h>
#include <hip/hip_bf16.h>
#include <math.h>

#define LNUM  6
#define HDIM  768
#define NHEAD 12
#define DHEAD 64
#define IDIM  3072
#define NB    16
#define SEQ   512
#define MTOK  (NB*SEQ)   // 8192
#define NQKV  (3*HDIM)   // 2304

typedef __bf16 bf16;
typedef __bf16 bf16x4 __attribute__((ext_vector_type(4)));
typedef __bf16 bf16x8 __attribute__((ext_vector_type(8)));
typedef float  f32x4  __attribute__((ext_vector_type(4)));

__device__ __forceinline__ void async_copy16(const bf16* g, bf16* l) {
  __builtin_amdgcn_global_load_lds((__attribute__((address_space(1))) void*)g,
                                   (__attribute__((address_space(3))) void*)l,
                                   16, 0, 0);
}

// fast gelu (tanh form): max abs err vs exact-erf gelu ~3e-3
__device__ __forceinline__ float gelu_fast(float t) {
  const float u = 0.7978845608f * (t + 0.044715f * t * t * t);
  const float e = __expf(-2.f * fabsf(u));
  const float th = (1.f - e) / (1.f + e);
  return 0.5f * t * (1.f + copysignf(th, u));
}

// =====================  dtype detector (f32 vs bf16 input)  ==================
__global__ void detect_k(const unsigned short* __restrict__ probe, int* __restrict__ flag)
{
  __shared__ int sc[4];
  const int tid = threadIdx.x;
  int cnt = 0;
#pragma unroll
  for (int j = 0; j < 16; j++) {
    const unsigned short w = probe[tid * 16 + j];
    const int e = (w >> 7) & 0xFF;
    cnt += (e >= 90 && e <= 130) ? 1 : 0;
  }
#pragma unroll
  for (int o = 32; o; o >>= 1) cnt += __shfl_xor(cnt, o);
  if ((tid & 63) == 0) sc[tid >> 6] = cnt;
  __syncthreads();
  if (tid == 0) flag[0] = ((sc[0] + sc[1] + sc[2] + sc[3]) < 3482) ? 1 : 0;
}

// =====================  normalize copies  =====================
__global__ void cvt1d_k(const void* __restrict__ src, bf16* __restrict__ dst,
                        int n, const int* __restrict__ flag)
{
  const int i = blockIdx.x * 256 + threadIdx.x;
  if (i < n)
    dst[i] = (*flag) ? (bf16)((const float*)src)[i] : ((const bf16*)src)[i];
}

// slice-copy [L][perL] -> dst[l*dstStride + off + c]   (for qkv bias concat)
__global__ void cvt_slice_k(const void* __restrict__ src, bf16* __restrict__ dst,
                            int perL, int off, int dstStride, int total,
                            const int* __restrict__ flag)
{
  const int i = blockIdx.x * 256 + threadIdx.x;
  if (i < total) {
    const int l = i / perL, c = i - l * perL;
    const bf16 v = (*flag) ? (bf16)((const float*)src)[i] : ((const bf16*)src)[i];
    dst[l * dstStride + off + c] = v;
  }
}

// ====  weight transpose+normalize: (K x N) -> (N x K) bf16, strided dst  =====
__global__ void wtrans_k(const void* __restrict__ src, bf16* __restrict__ dst,
                         int K, int N, int layer, int dstLS, int dstOff,
                         const int* __restrict__ flag)
{
  __shared__ bf16 t[32][33];
  const size_t sOff = (size_t)(blockIdx.z + layer) * K * N;
  const size_t dOff = (size_t)blockIdx.z * dstLS + dstOff;
  const int n0 = blockIdx.x * 32, k0 = blockIdx.y * 32;
  const int tx = threadIdx.x, ty = threadIdx.y;   // (32,8)
  const int f = *flag;
#pragma unroll
  for (int i = 0; i < 4; i++) {
    const size_t idx = sOff + (size_t)(k0 + ty*4 + i) * N + n0 + tx;
    t[ty*4+i][tx] = f ? (bf16)((const float*)src)[idx] : ((const bf16*)src)[idx];
  }
  __syncthreads();
#pragma unroll
  for (int i = 0; i < 4; i++)
    dst[dOff + (size_t)(n0 + ty*4 + i) * K + k0 + tx] = t[tx][ty*4+i];
}

// =====================  MFMA GEMM, B^T (N x K) input, 128x128 2-phase  =======
// (kept for Wo / Wo2 where N=768 gives only 96 tiles of 256^2)
template<int BM, int BN, int MT, int NT, int EPI, int XS>
__global__ __launch_bounds__(256)
void gemm_bt(const bf16* __restrict__ A, const bf16* __restrict__ Bt,
             float* __restrict__ Cf, bf16* __restrict__ Cb,
             bf16* __restrict__ Cb2, bf16* __restrict__ Cb3,
             const bf16* __restrict__ bias, const bf16* __restrict__ res,
             int K, int sA, int sB, int sC)
{
  __shared__ __align__(16) bf16 ldsA[BM*32];
  __shared__ __align__(16) bf16 ldsB[BN*32];
  const int tid  = threadIdx.x;
  const int wave = tid >> 6;
  const int lane = tid & 63;
  const int quad = lane >> 4;
  const int l16  = lane & 15;
  const int wm = wave >> 1, wn = wave & 1;   // 2x2 wave grid
  const int swz = (l16 >> 1) & 3;            // read-side XOR swizzle key

  int bx = blockIdx.x, by = blockIdx.y;
  if (XS) {
    if ((gridDim.y & 7) == 0) {
      const int id  = by * gridDim.x + bx;
      const int xcd = id & 7, slot = id >> 3;
      bx = slot % gridDim.x;
      by = (slot / gridDim.x) * 8 + xcd;
    }
  }
  const int m0 = by * BM;
  const int n0 = bx * BN;
  const int srow = tid >> 2;
  const int scol = (((tid & 3) ^ ((tid >> 3) & 3))) * 8;   // swizzled gather

  const bf16* gA = A + (size_t)(m0 + srow) * sA + scol;
  const bf16* gB = Bt + (size_t)(n0 + srow) * sB + scol;
  bf16* lA = &ldsA[(wave * 16) * 32];
  bf16* lB = &ldsB[(wave * 16) * 32];

  f32x4 acc[MT][NT];
  const f32x4 fzero = {0.f, 0.f, 0.f, 0.f};
#pragma unroll
  for (int i = 0; i < MT; i++)
#pragma unroll
    for (int j = 0; j < NT; j++) acc[i][j] = fzero;

  for (int k0 = 0; k0 < K; k0 += 32) {
#pragma unroll
    for (int p = 0; p < BM/64; p++)
      async_copy16(gA + (size_t)p * 64 * sA + k0, lA + p * 64 * 32);
#pragma unroll
    for (int p = 0; p < BN/64; p++)
      async_copy16(gB + (size_t)p * 64 * sB + k0, lB + p * 64 * 32);
    __syncthreads();

    bf16x8 af[MT], bfv[NT];
#pragma unroll
    for (int i = 0; i < MT; i++)
      af[i] = *(const bf16x8*)&ldsA[(wm*(MT*16) + i*16 + l16) * 32 + (quad ^ swz) * 8];
#pragma unroll
    for (int j = 0; j < NT; j++)
      bfv[j] = *(const bf16x8*)&ldsB[(wn*(NT*16) + j*16 + l16) * 32 + (quad ^ swz) * 8];
#pragma unroll
    for (int i = 0; i < MT; i++)
#pragma unroll
      for (int j = 0; j < NT; j++)
        acc[i][j] = __builtin_amdgcn_mfma_f32_16x16x32_bf16(af[i], bfv[j], acc[i][j], 0, 0, 0);
    __syncthreads();
  }

  // epilogue: C/D layout col=lane&15, row=quad*4+reg
#pragma unroll
  for (int i = 0; i < MT; i++) {
    const int mtile = m0 + wm*(MT*16) + i*16 + quad*4;
#pragma unroll
    for (int j = 0; j < NT; j++) {
      const int nn = n0 + wn*(NT*16) + j*16 + l16;
      const float bv = bias ? (float)bias[nn] : 0.f;
      if (EPI == 5) {
        if (nn < HDIM) {
#pragma unroll
          for (int r = 0; r < 4; r++)
            Cb[(size_t)(mtile + r) * HDIM + nn] = (bf16)((acc[i][j][r] + bv) * 0.125f);
        } else if (nn < 2*HDIM) {
#pragma unroll
          for (int r = 0; r < 4; r++)
            Cb2[(size_t)(mtile + r) * HDIM + (nn - HDIM)] = (bf16)(acc[i][j][r] + bv);
        } else {
          const int nn2 = nn - 2*HDIM;
          const int bb = mtile >> 9, s = mtile & 511;
          const int hh = nn2 >> 6, dd = nn2 & 63;
          const size_t base = ((size_t)(bb*NHEAD + hh) * DHEAD + dd) * SEQ + s;
          bf16x4 pk;
#pragma unroll
          for (int r = 0; r < 4; r++) pk[r] = (bf16)(acc[i][j][r] + bv);
          *(bf16x4*)(Cb3 + base) = pk;
        }
      } else {
#pragma unroll
        for (int r = 0; r < 4; r++) {
          const int mm = mtile + r;
          const size_t idx = (size_t)mm * sC + nn;
          const float v = acc[i][j][r];
          if (EPI == 2) Cf[idx] = v + bv + (float)res[idx];
          else if (EPI == 3) Cb[idx] = (bf16)gelu_fast(v + bv);
        }
      }
    }
  }
}

// =====================  256x256 8-phase MFMA GEMM (T2+T3+T4+T5)  =============
// 8 waves (2M x 4N), 512 thr, BK=64, LDS 128 KiB (A/B double-buffered K-tiles).
// Per-wave output 128x64: Mfrag 0..7, Nfrag 0..3.
// LDS layout: [256 rows][8 slots of 16B], slot' = slot ^ (row&7)  (2-way max
// bank aliasing on ds_read_b128 = free). Staging is LINEAR dest via
// global_load_lds width=16 with inverse-swizzled GLOBAL source (G21).
// Phase schedule per K-tile t (buf b = t&1):
//   p0: read aF=A[m-half0](8) + bA=B[n-half0](4); stage A(t+1) h0 -> buf b^1
//       [mfma acc[0..3][0..1]]
//   p1: read bB=B[n-half1](4);                    stage A(t+1) h1 -> buf b^1
//       [mfma acc[0..3][2..3]]
//   p2: read aF=A[m-half1](8, reuse regs);        stage B(t+2) h0 -> buf b
//       [mfma acc[4..7][2..3]]   (B region of buf b fully read by end of p1)
//   p3: (no reads);                               stage B(t+2) h1 -> buf b
//       [mfma acc[4..7][0..1]]
//   end: s_waitcnt vmcnt(4)  (retires A(t+1),B(t+1); keeps B(t+2) in flight —
//        NEVER drains to 0 mid-loop), s_barrier.
// In-flight steady state F(t) = {B(t+1)} = 4 loads.
template<int EPI>
__global__ __launch_bounds__(512, 2)
void gemm256(const bf16* __restrict__ A, const bf16* __restrict__ Bt,
             float* __restrict__ Cf, bf16* __restrict__ Cb,
             bf16* __restrict__ Cb2, bf16* __restrict__ Cb3,
             const bf16* __restrict__ bias, const bf16* __restrict__ res,
             int K, int sA, int sB, int sC)
{
  __shared__ __align__(16) bf16 As[2][256*64];
  __shared__ __align__(16) bf16 Bs[2][256*64];

  const int tid  = threadIdx.x;
  const int wave = tid >> 6;
  const int lane = tid & 63;
  const int quad = lane >> 4;
  const int l16  = lane & 15;
  const int wm   = wave >> 2;       // 0..1
  const int wn   = wave & 3;        // 0..3

  int bx = blockIdx.x, by = blockIdx.y;
  if ((gridDim.y & 7) == 0) {       // bijective XCD swizzle (grid%8==0)
    const int id  = by * gridDim.x + bx;
    const int xcd = id & 7, slot = id >> 3;
    bx = slot % gridDim.x;
    by = (slot / gridDim.x) * 8 + xcd;
  }
  const int m0 = by * 256;
  const int n0 = bx * 256;

  // ---- staging addressing: thread tid, load i covers LDS element
  // (i*512+tid)*8 of the half; global col-group pre-swizzled (inverse XOR).
  const int rb  = tid >> 3;             // row-in-half base (0..63), +64 for i=1
  const int sb  = tid & 7;              // LDS slot (linear dest)
  const int sbx = sb ^ (rb & 7);        // swizzled source col-group
  const bf16* gA = A  + (size_t)(m0 + rb) * sA + sbx * 8;
  const bf16* gB = Bt + (size_t)(n0 + rb) * sB + sbx * 8;

  auto stgA = [&](int buf, int h, int kt2) {
#pragma unroll
    for (int i = 0; i < 2; i++)
      async_copy16(gA + (size_t)(h*128 + i*64) * sA + kt2*64,
                   &As[buf][h*8192 + i*4096 + tid*8]);
  };
  auto stgB = [&](int buf, int h, int kt2) {
#pragma unroll
    for (int i = 0; i < 2; i++)
      async_copy16(gB + (size_t)(h*128 + i*64) * sB + kt2*64,
                   &Bs[buf][h*8192 + i*4096 + tid*8]);
  };

  // ---- read-side swizzled slot per ksub (row&7 == l16&7 for all frags)
  const int s7  = l16 & 7;
  const int sl0 = (0 + quad) ^ s7;
  const int sl1 = (4 + quad) ^ s7;

  f32x4 acc[8][4];
  const f32x4 fzero = {0.f, 0.f, 0.f, 0.f};
#pragma unroll
  for (int i = 0; i < 8; i++)
#pragma unroll
    for (int j = 0; j < 4; j++) acc[i][j] = fzero;

  bf16x8 aF[2][4], bA[2][2], bB[2][2];

  const int NKT = K >> 6;

  // ---- prologue: tile0 A+B, tile1 B.  vmcnt(4) keeps B(1) in flight.
  stgA(0, 0, 0); stgA(0, 1, 0);
  stgB(0, 0, 0); stgB(0, 1, 0);
  if (NKT > 1) { stgB(1, 0, 1); stgB(1, 1, 1); }
  if (NKT > 1) asm volatile("s_waitcnt vmcnt(4)" ::: "memory");
  else         asm volatile("s_waitcnt vmcnt(0)" ::: "memory");
  __builtin_amdgcn_s_barrier();

  for (int kt = 0; kt < NKT; kt++) {
    const int b = kt & 1;

    // ---------------- phase 0 ----------------
#pragma unroll
    for (int f = 0; f < 4; f++) {
      const int row = (wm*128 + f*16 + l16) * 64;
      aF[0][f] = *(const bf16x8*)&As[b][row + sl0*8];
      aF[1][f] = *(const bf16x8*)&As[b][row + sl1*8];
    }
#pragma unroll
    for (int nf = 0; nf < 2; nf++) {
      const int row = (wn*64 + nf*16 + l16) * 64;
      bA[0][nf] = *(const bf16x8*)&Bs[b][row + sl0*8];
      bA[1][nf] = *(const bf16x8*)&Bs[b][row + sl1*8];
    }
    if (kt + 1 < NKT) stgA(b ^ 1, 0, kt + 1);
    asm volatile("s_waitcnt lgkmcnt(8)" ::: "memory");
    __builtin_amdgcn_s_barrier();
    asm volatile("s_waitcnt lgkmcnt(0)" ::: "memory");
    __builtin_amdgcn_s_setprio(1);
#pragma unroll
    for (int ks = 0; ks < 2; ks++)
#pragma unroll
      for (int f = 0; f < 4; f++)
#pragma unroll
        for (int nf = 0; nf < 2; nf++)
          acc[f][nf] = __builtin_amdgcn_mfma_f32_16x16x32_bf16(
              aF[ks][f], bA[ks][nf], acc[f][nf], 0, 0, 0);
    __builtin_amdgcn_s_setprio(0);
    __builtin_amdgcn_s_barrier();

    // ---------------- phase 1 ----------------
#pragma unroll
    for (int nf = 0; nf < 2; nf++) {
      const int row = (wn*64 + 32 + nf*16 + l16) * 64;
      bB[0][nf] = *(const bf16x8*)&Bs[b][row + sl0*8];
      bB[1][nf] = *(const bf16x8*)&Bs[b][row + sl1*8];
    }
    if (kt + 1 < NKT) stgA(b ^ 1, 1, kt + 1);
    __builtin_amdgcn_s_barrier();
    asm volatile("s_waitcnt lgkmcnt(0)" ::: "memory");
    __builtin_amdgcn_s_setprio(1);
#pragma unroll
    for (int ks = 0; ks < 2; ks++)
#pragma unroll
      for (int f = 0; f < 4; f++)
#pragma unroll
        for (int nf = 0; nf < 2; nf++)
          acc[f][2 + nf] = __builtin_amdgcn_mfma_f32_16x16x32_bf16(
              aF[ks][f], bB[ks][nf], acc[f][2 + nf], 0, 0, 0);
    __builtin_amdgcn_s_setprio(0);
    __builtin_amdgcn_s_barrier();

    // ---------------- phase 2 ----------------
#pragma unroll
    for (int f = 0; f < 4; f++) {
      const int row = (wm*128 + 64 + f*16 + l16) * 64;
      aF[0][f] = *(const bf16x8*)&As[b][row + sl0*8];
      aF[1][f] = *(const bf16x8*)&As[b][row + sl1*8];
    }
    if (kt + 2 < NKT) stgB(b, 0, kt + 2);
    __builtin_amdgcn_s_barrier();
    asm volatile("s_waitcnt lgkmcnt(0)" ::: "memory");
    __builtin_amdgcn_s_setprio(1);
#pragma unroll
    for (int ks = 0; ks < 2; ks++)
#pragma unroll
      for (int f = 0; f < 4; f++)
#pragma unroll
        for (int nf = 0; nf < 2; nf++)
          acc[4 + f][2 + nf] = __builtin_amdgcn_mfma_f32_16x16x32_bf16(
              aF[ks][f], bB[ks][nf], acc[4 + f][2 + nf], 0, 0, 0);
    __builtin_amdgcn_s_setprio(0);
    __builtin_amdgcn_s_barrier();

    // ---------------- phase 3 ----------------
    if (kt + 2 < NKT) stgB(b, 1, kt + 2);
    __builtin_amdgcn_s_barrier();
    __builtin_amdgcn_s_setprio(1);
#pragma unroll
    for (int ks = 0; ks < 2; ks++)
#pragma unroll
      for (int f = 0; f < 4; f++)
#pragma unroll
        for (int nf = 0; nf < 2; nf++)
          acc[4 + f][nf] = __builtin_amdgcn_mfma_f32_16x16x32_bf16(
              aF[ks][f], bA[ks][nf], acc[4 + f][nf], 0, 0, 0);
    __builtin_amdgcn_s_setprio(0);
    if (kt + 2 < NKT) asm volatile("s_waitcnt vmcnt(4)" ::: "memory");
    else              asm volatile("s_waitcnt vmcnt(0)" ::: "memory");
    __builtin_amdgcn_s_barrier();
  }

  // ---- epilogue: C/D layout col=lane&15, row=quad*4+reg
#pragma unroll
  for (int mf = 0; mf < 8; mf++) {
    const int mtile = m0 + wm*128 + mf*16 + quad*4;
#pragma unroll
    for (int nf = 0; nf < 4; nf++) {
      const int nn = n0 + wn*64 + nf*16 + l16;
      const float bv = bias ? (float)bias[nn] : 0.f;
      if (EPI == 5) {
        if (nn < HDIM) {
#pragma unroll
          for (int r = 0; r < 4; r++)
            Cb[(size_t)(mtile + r) * HDIM + nn] = (bf16)((acc[mf][nf][r] + bv) * 0.125f);
        } else if (nn < 2*HDIM) {
#pragma unroll
          for (int r = 0; r < 4; r++)
            Cb2[(size_t)(mtile + r) * HDIM + (nn - HDIM)] = (bf16)(acc[mf][nf][r] + bv);
        } else {
          const int nn2 = nn - 2*HDIM;
          const int bb = mtile >> 9, s = mtile & 511;
          const int hh = nn2 >> 6, dd = nn2 & 63;
          const size_t base = ((size_t)(bb*NHEAD + hh) * DHEAD + dd) * SEQ + s;
          bf16x4 pk;
#pragma unroll
          for (int r = 0; r < 4; r++) pk[r] = (bf16)(acc[mf][nf][r] + bv);
          *(bf16x4*)(Cb3 + base) = pk;
        }
      } else if (EPI == 3) {
#pragma unroll
        for (int r = 0; r < 4; r++)
          Cb[(size_t)(mtile + r) * sC + nn] = (bf16)gelu_fast(acc[mf][nf][r] + bv);
      } else if (EPI == 2) {
#pragma unroll
        for (int r = 0; r < 4; r++) {
          const size_t idx = (size_t)(mtile + r) * sC + nn;
          Cf[idx] = acc[mf][nf][r] + bv + (float)res[idx];
        }
      }
    }
  }
}

// =====================  fused flash attention  =====================
__global__ __launch_bounds__(256)
void flash_k(const bf16* __restrict__ qb, const bf16* __restrict__ kb,
             const bf16* __restrict__ vt, bf16* __restrict__ ctxb)
{
  __shared__ __align__(16) bf16 Qs[128][72];
  __shared__ __align__(16) bf16 Ks[64][72];
  __shared__ __align__(16) bf16 Vs[64][72];
  __shared__ __align__(16) bf16 Ps[128][72];
  const int tid = threadIdx.x;
  const int wave = tid >> 6, lane = tid & 63;
  const int quad = lane >> 4, l16 = lane & 15;
  const int z = blockIdx.y;
  const int b = z / NHEAD, h = z - b * NHEAD;
  const int qt = blockIdx.x;
  const size_t qRow0 = (size_t)b * SEQ + qt * 128;

#pragma unroll
  for (int r = 0; r < 4; r++) {
    const int idx = tid + r * 256;
    const int row = idx >> 3, c8 = (idx & 7) * 8;
    *(bf16x8*)&Qs[row][c8] =
        *(const bf16x8*)&qb[(qRow0 + row) * HDIM + h * DHEAD + c8];
  }

  f32x4 Oacc[2][4];
  float mrow[2][4], lrow[2][4];
#pragma unroll
  for (int i = 0; i < 2; i++)
#pragma unroll
    for (int n = 0; n < 4; n++) Oacc[i][n] = (f32x4){0.f,0.f,0.f,0.f};
#pragma unroll
  for (int i = 0; i < 2; i++)
#pragma unroll
    for (int r = 0; r < 4; r++) { mrow[i][r] = -3.0e38f; lrow[i][r] = 0.f; }

  for (int j = 0; j < 8; j++) {
    __syncthreads();
#pragma unroll
    for (int r = 0; r < 2; r++) {
      const int idx = tid + r * 256;
      const int row = idx >> 3, c8 = (idx & 7) * 8;
      *(bf16x8*)&Ks[row][c8] =
          *(const bf16x8*)&kb[((size_t)b*SEQ + j*64 + row) * HDIM + h*DHEAD + c8];
      *(bf16x8*)&Vs[row][c8] =
          *(const bf16x8*)&vt[((size_t)z*DHEAD + row) * SEQ + j*64 + c8];
    }
    __syncthreads();

    f32x4 Sacc[2][4];
#pragma unroll
    for (int i = 0; i < 2; i++)
#pragma unroll
      for (int n = 0; n < 4; n++) Sacc[i][n] = (f32x4){0.f,0.f,0.f,0.f};
#pragma unroll
    for (int kk = 0; kk < 2; kk++) {
      bf16x8 af[2], bv[4];
#pragma unroll
      for (int i = 0; i < 2; i++)
        af[i] = *(const bf16x8*)&Qs[wave*32 + i*16 + l16][kk*32 + quad*8];
#pragma unroll
      for (int n = 0; n < 4; n++)
        bv[n] = *(const bf16x8*)&Ks[n*16 + l16][kk*32 + quad*8];
#pragma unroll
      for (int i = 0; i < 2; i++)
#pragma unroll
        for (int n = 0; n < 4; n++)
          Sacc[i][n] = __builtin_amdgcn_mfma_f32_16x16x32_bf16(af[i], bv[n], Sacc[i][n], 0,0,0);
    }

    float alpha[2][4];
#pragma unroll
    for (int i = 0; i < 2; i++)
#pragma unroll
      for (int r = 0; r < 4; r++) {
        float mx = Sacc[i][0][r];
#pragma unroll
        for (int n = 1; n < 4; n++) mx = fmaxf(mx, Sacc[i][n][r]);
#pragma unroll
        for (int o = 8; o; o >>= 1) mx = fmaxf(mx, __shfl_xor(mx, o));
        const float mn = fmaxf(mrow[i][r], mx);
        const float a = __expf(mrow[i][r] - mn);
        float rs = 0.f;
#pragma unroll
        for (int n = 0; n < 4; n++) {
          const float p = __expf(Sacc[i][n][r] - mn);
          Sacc[i][n][r] = p; rs += p;
        }
#pragma unroll
        for (int o = 8; o; o >>= 1) rs += __shfl_xor(rs, o);
        lrow[i][r] = lrow[i][r] * a + rs;
        mrow[i][r] = mn;
        alpha[i][r] = a;
      }

#pragma unroll
    for (int i = 0; i < 2; i++)
#pragma unroll
      for (int n = 0; n < 4; n++)
#pragma unroll
        for (int r = 0; r < 4; r++)
          Ps[wave*32 + i*16 + quad*4 + r][n*16 + l16] = (bf16)Sacc[i][n][r];
    __syncthreads();

#pragma unroll
    for (int i = 0; i < 2; i++)
#pragma unroll
      for (int n = 0; n < 4; n++)
#pragma unroll
        for (int r = 0; r < 4; r++) Oacc[i][n][r] *= alpha[i][r];
#pragma unroll
    for (int kk = 0; kk < 2; kk++) {
      bf16x8 af[2], bv[4];
#pragma unroll
      for (int i = 0; i < 2; i++)
        af[i] = *(const bf16x8*)&Ps[wave*32 + i*16 + l16][kk*32 + quad*8];
#pragma unroll
      for (int n = 0; n < 4; n++)
        bv[n] = *(const bf16x8*)&Vs[n*16 + l16][kk*32 + quad*8];
#pragma unroll
      for (int i = 0; i < 2; i++)
#pragma unroll
        for (int n = 0; n < 4; n++)
          Oacc[i][n] = __builtin_amdgcn_mfma_f32_16x16x32_bf16(af[i], bv[n], Oacc[i][n], 0,0,0);
    }
  }

#pragma unroll
  for (int i = 0; i < 2; i++)
#pragma unroll
    for (int r = 0; r < 4; r++) {
      const float inv = 1.f / lrow[i][r];
      const size_t tok = qRow0 + wave*32 + i*16 + quad*4 + r;
#pragma unroll
      for (int n = 0; n < 4; n++)
        ctxb[tok * HDIM + h*DHEAD + n*16 + l16] = (bf16)(Oacc[i][n][r] * inv);
    }
}

// ========  LayerNorm over H=768, fp32 in, bf16 out (+ optional d_out)  ========
__global__ void layernorm_k(const float* __restrict__ x, const bf16* __restrict__ g,
                            const bf16* __restrict__ b, bf16* __restrict__ yb,
                            void* __restrict__ dout, int last, const int* __restrict__ flag)
{
  __shared__ float sred[4];
  const int row = blockIdx.x;
  const int tid = threadIdx.x;
  const float* xr = x + (size_t)row * HDIM;
  const float v0 = xr[tid], v1 = xr[tid+256], v2 = xr[tid+512];
  float s = v0 + v1 + v2;
#pragma unroll
  for (int o = 32; o; o >>= 1) s += __shfl_xor(s, o);
  if ((tid & 63) == 0) sred[tid >> 6] = s;
  __syncthreads();
  const float mean = (sred[0]+sred[1]+sred[2]+sred[3]) * (1.f/768.f);
  __syncthreads();
  const float d0 = v0-mean, d1 = v1-mean, d2 = v2-mean;
  float vs = d0*d0 + d1*d1 + d2*d2;
#pragma unroll
  for (int o = 32; o; o >>= 1) vs += __shfl_xor(vs, o);
  if ((tid & 63) == 0) sred[tid >> 6] = vs;
  __syncthreads();
  const float var = (sred[0]+sred[1]+sred[2]+sred[3]) * (1.f/768.f);
  const float rs  = rsqrtf(var + 1e-12f);
  const float y0 = d0*rs*(float)g[tid]     + (float)b[tid];
  const float y1 = d1*rs*(float)g[tid+256] + (float)b[tid+256];
  const float y2 = d2*rs*(float)g[tid+512] + (float)b[tid+512];
  bf16* ybr = yb + (size_t)row * HDIM;
  ybr[tid]     = (bf16)y0;
  ybr[tid+256] = (bf16)y1;
  ybr[tid+512] = (bf16)y2;
  if (last) {
    if (*flag) {
      float* o = (float*)dout + (size_t)row * HDIM;
      o[tid] = y0; o[tid+256] = y1; o[tid+512] = y2;
    } else {
      bf16* o = (bf16*)dout + (size_t)row * HDIM;
      o[tid] = (bf16)y0; o[tid+256] = (bf16)y1; o[tid+512] = (bf16)y2;
    }
  }
}

// ============================================================================
extern "C" void kernel_launch(void* const* d_in, const int* in_sizes, int n_in,
                              void* d_out, int out_size, void* d_ws, size_t ws_size,
                              hipStream_t stream)
{
  (void)in_sizes; (void)n_in; (void)out_size;

  char* ws = (char*)d_ws;
  size_t off = 0;
  auto carve = [&](size_t bytes) -> char* {
    char* p = ws + off; off += (bytes + 255) & ~(size_t)255; return p;
  };
  int*   flag = (int*)carve(256);
  bf16*  hcur = (bf16*)carve((size_t)MTOK*HDIM*2);
  bf16*  qb   = (bf16*)carve((size_t)MTOK*HDIM*2);
  bf16*  kb   = (bf16*)carve((size_t)MTOK*HDIM*2);
  bf16*  vt   = (bf16*)carve((size_t)MTOK*HDIM*2);
  bf16*  ctxb = (bf16*)carve((size_t)MTOK*HDIM*2);
  float* x1   = (float*)carve((size_t)MTOK*HDIM*4);
  bf16*  aob  = kb;   // kb dead once flash attention of the layer is complete

  bf16* nbqkv = (bf16*)carve((size_t)LNUM*NQKV*2);
  bf16* nbo   = (bf16*)carve((size_t)LNUM*HDIM*2);
  bf16* ng1   = (bf16*)carve((size_t)LNUM*HDIM*2);
  bf16* nb1   = (bf16*)carve((size_t)LNUM*HDIM*2);
  bf16* nbi   = (bf16*)carve((size_t)LNUM*IDIM*2);
  bf16* nbo2  = (bf16*)carve((size_t)LNUM*HDIM*2);
  bf16* ng2   = (bf16*)carve((size_t)LNUM*HDIM*2);
  bf16* nb2   = (bf16*)carve((size_t)LNUM*HDIM*2);

  const size_t wAllBytes = (size_t)LNUM*(NQKV*HDIM + HDIM*HDIM + 2*HDIM*IDIM)*2; // ~84.9MB
  const bool preAll = ws_size >= off + wAllBytes + (size_t)256*IDIM*2 + (1u<<20);
  bf16 *wqkvt=0, *wot=0, *wit=0, *wo2t=0, *bufA=0, *bufB=0;
  if (preAll) {
    wqkvt = (bf16*)carve((size_t)LNUM*NQKV*HDIM*2);
    wot   = (bf16*)carve((size_t)LNUM*HDIM*HDIM*2);
    wit   = (bf16*)carve((size_t)LNUM*HDIM*IDIM*2);
    wo2t  = (bf16*)carve((size_t)LNUM*HDIM*IDIM*2);
  } else {
    bufA = (bf16*)carve((size_t)HDIM*IDIM*2);
    bufB = (bf16*)carve((size_t)HDIM*IDIM*2);
  }

  const size_t unionAvail = (ws_size > off) ? (ws_size - off) : 0;
  int RM = 256;
  { const int rms[6] = {8192,4096,2048,1024,512,256};
    for (int i = 0; i < 6; i++)
      if ((size_t)rms[i]*IDIM*2 <= unionAvail) { RM = rms[i]; break; } }
  bf16* interb = (bf16*)(ws + off);

  // ---------------- normalize inputs ----------------------------------------
  detect_k<<<1, 256, 0, stream>>>((const unsigned short*)d_in[1], flag);
  cvt1d_k<<<(MTOK*HDIM+255)/256, 256, 0, stream>>>(d_in[0], hcur, MTOK*HDIM, flag);
  cvt_slice_k<<<(LNUM*HDIM+255)/256, 256, 0, stream>>>(d_in[2], nbqkv, HDIM, 0,      NQKV, LNUM*HDIM, flag);
  cvt_slice_k<<<(LNUM*HDIM+255)/256, 256, 0, stream>>>(d_in[4], nbqkv, HDIM, HDIM,   NQKV, LNUM*HDIM, flag);
  cvt_slice_k<<<(LNUM*HDIM+255)/256, 256, 0, stream>>>(d_in[6], nbqkv, HDIM, 2*HDIM, NQKV, LNUM*HDIM, flag);
  cvt1d_k<<<(LNUM*HDIM+255)/256, 256, 0, stream>>>(d_in[8],  nbo,  LNUM*HDIM, flag);
  cvt1d_k<<<(LNUM*HDIM+255)/256, 256, 0, stream>>>(d_in[9],  ng1,  LNUM*HDIM, flag);
  cvt1d_k<<<(LNUM*HDIM+255)/256, 256, 0, stream>>>(d_in[10], nb1,  LNUM*HDIM, flag);
  cvt1d_k<<<(LNUM*IDIM+255)/256, 256, 0, stream>>>(d_in[12], nbi,  LNUM*IDIM, flag);
  cvt1d_k<<<(LNUM*HDIM+255)/256, 256, 0, stream>>>(d_in[14], nbo2, LNUM*HDIM, flag);
  cvt1d_k<<<(LNUM*HDIM+255)/256, 256, 0, stream>>>(d_in[15], ng2,  LNUM*HDIM, flag);
  cvt1d_k<<<(LNUM*HDIM+255)/256, 256, 0, stream>>>(d_in[16], nb2,  LNUM*HDIM, flag);

  const dim3 tb(32, 8);
  if (preAll) {
    wtrans_k<<<dim3(HDIM/32, HDIM/32, LNUM), tb, 0, stream>>>(d_in[1], wqkvt, HDIM, HDIM, 0, NQKV*HDIM, 0,           flag);
    wtrans_k<<<dim3(HDIM/32, HDIM/32, LNUM), tb, 0, stream>>>(d_in[3], wqkvt, HDIM, HDIM, 0, NQKV*HDIM, HDIM*HDIM,   flag);
    wtrans_k<<<dim3(HDIM/32, HDIM/32, LNUM), tb, 0, stream>>>(d_in[5], wqkvt, HDIM, HDIM, 0, NQKV*HDIM, 2*HDIM*HDIM, flag);
    wtrans_k<<<dim3(HDIM/32, HDIM/32, LNUM), tb, 0, stream>>>(d_in[7], wot,  HDIM, HDIM, 0, HDIM*HDIM, 0, flag);
    wtrans_k<<<dim3(IDIM/32, HDIM/32, LNUM), tb, 0, stream>>>(d_in[11], wit,  HDIM, IDIM, 0, HDIM*IDIM, 0, flag);
    wtrans_k<<<dim3(HDIM/32, IDIM/32, LNUM), tb, 0, stream>>>(d_in[13], wo2t, IDIM, HDIM, 0, HDIM*IDIM, 0, flag);
  }

  for (int l = 0; l < LNUM; l++) {
    const bf16* hin = hcur;

    // ---- fused QKV (256^2 8-phase, grid 9x32 = 288 blocks) ----
    const bf16* WqkvT;
    if (preAll) WqkvT = wqkvt + (size_t)l * NQKV * HDIM;
    else {
      wtrans_k<<<dim3(HDIM/32, HDIM/32, 1), tb, 0, stream>>>(d_in[1], bufA, HDIM, HDIM, l, 0, 0,           flag);
      wtrans_k<<<dim3(HDIM/32, HDIM/32, 1), tb, 0, stream>>>(d_in[3], bufA, HDIM, HDIM, l, 0, HDIM*HDIM,   flag);
      wtrans_k<<<dim3(HDIM/32, HDIM/32, 1), tb, 0, stream>>>(d_in[5], bufA, HDIM, HDIM, l, 0, 2*HDIM*HDIM, flag);
      WqkvT = bufA;
    }
    gemm256<5><<<dim3(NQKV/256, MTOK/256), 512, 0, stream>>>(
        hin, WqkvT, nullptr, qb, kb, vt, nbqkv + (size_t)l*NQKV, nullptr,
        HDIM, HDIM, HDIM, HDIM);

    // ---- fused flash attention ----
    flash_k<<<dim3(SEQ/128, NB*NHEAD), 256, 0, stream>>>(qb, kb, vt, ctxb);

    // ---- x1 = ctx@Wo + bo + h ; attn_out = LN(x1) -> aob ----
    const bf16* WoT;
    if (preAll) WoT = wot + (size_t)l * HDIM * HDIM;
    else {
      wtrans_k<<<dim3(HDIM/32, HDIM/32, 1), tb, 0, stream>>>(d_in[7], bufA, HDIM, HDIM, l, 0, 0, flag);
      WoT = bufA;
    }
    gemm_bt<128,128,4,4,2,1><<<dim3(HDIM/128, MTOK/128), 256, 0, stream>>>(
        ctxb, WoT, x1, nullptr, nullptr, nullptr, nbo + l*HDIM, hin,
        HDIM, HDIM, HDIM, HDIM);
    layernorm_k<<<MTOK, 256, 0, stream>>>(x1, ng1 + l*HDIM, nb1 + l*HDIM, aob,
                                          d_out, 0, flag);

    // ---- FFN ----
    const bf16 *WiT, *Wo2T;
    if (preAll) { WiT = wit + (size_t)l*HDIM*IDIM; Wo2T = wo2t + (size_t)l*HDIM*IDIM; }
    else {
      wtrans_k<<<dim3(IDIM/32, HDIM/32, 1), tb, 0, stream>>>(d_in[11], bufA, HDIM, IDIM, l, 0, 0, flag);
      wtrans_k<<<dim3(HDIM/32, IDIM/32, 1), tb, 0, stream>>>(d_in[13], bufB, IDIM, HDIM, l, 0, 0, flag);
      WiT = bufA; Wo2T = bufB;
    }
    for (int r0 = 0; r0 < MTOK; r0 += RM) {
      gemm256<3><<<dim3(IDIM/256, RM/256), 512, 0, stream>>>(
          aob + (size_t)r0*HDIM, WiT, nullptr, interb, nullptr, nullptr,
          nbi + (size_t)l*IDIM, nullptr, HDIM, HDIM, HDIM, IDIM);
      gemm_bt<128,128,4,4,2,1><<<dim3(HDIM/128, RM/128), 256, 0, stream>>>(
          interb, Wo2T, x1 + (size_t)r0*HDIM, nullptr, nullptr, nullptr,
          nbo2 + l*HDIM, aob + (size_t)r0*HDIM, IDIM, IDIM, IDIM, HDIM);
    }
    layernorm_k<<<MTOK, 256, 0, stream>>>(x1, ng2 + l*HDIM, nb2 + l*HDIM, hcur,
                                          d_out, (l == LNUM-1) ? 1 : 0, flag);
  }
}